// Round 10
// baseline (1862.473 us; speedup 1.0000x reference)
//
#include <hip/hip_runtime.h>

#define NPTS   16384
#define RPB    256      // rows per block (4 waves x 64)
#define CPB    512      // cols per block
#define NRB    (NPTS / RPB)   // 64
#define NCB    (NPTS / CPB)   // 32

typedef short  bf16x8 __attribute__((ext_vector_type(8)));
typedef float  f32x16 __attribute__((ext_vector_type(16)));

// ---- bf16 split helpers (RNE) ----
__device__ __forceinline__ unsigned rne_bf16(float f) {
    unsigned u = __float_as_uint(f);
    return (u + 0x7fffu + ((u >> 16) & 1u)) >> 16;
}
__device__ __forceinline__ float bf16_dec(unsigned h) {
    return __uint_as_float(h << 16);
}
#define ONE_BF 0x3f80u

// K=16 slot map (A = weighted pred, B = plain tgt):
//  k0-3: ah*bh  k4-7: al*bh  k8-11: ah*bl  k12-13: 1*Tnh,1*Tnl  k14-15: Pnh*1,Pnl*1
// => acc = hi-precision dot + Tn_j + Pn_i = combined(i,j) directly.
// combined() is symmetric in (pred,tgt): row-mins of M = min_p2g,
// col-mins of M = min_g2p. ONE pass serves both directions.

__global__ __launch_bounds__(256) void prep_kernel(
    const float4* __restrict__ pred, const float4* __restrict__ tgt,
    uint4* __restrict__ wpred, uint4* __restrict__ ptgt,
    unsigned int* __restrict__ minbuf)
{
    int i = blockIdx.x * 256 + threadIdx.x;
    if (i >= NPTS) return;

    minbuf[i]        = 0x7f7f7f7fu;   // 3.39e38f
    minbuf[i + NPTS] = 0x7f7f7f7fu;

    unsigned onepk = ONE_BF | (ONE_BF << 16);

    {   // weighted pred record (row side)
        float4 v = pred[i];
        float n = fmaf(v.x, v.x, fmaf(v.y, v.y, fmaf(v.z, v.z, 0.5f * v.w * v.w)));
        unsigned nh = rne_bf16(n);
        unsigned nl = rne_bf16(n - bf16_dec(nh));
        unsigned npk = nh | (nl << 16);
        float w0 = -2.0f * v.x, w1 = -2.0f * v.y, w2 = -2.0f * v.z, w3 = -v.w;
        unsigned h0 = rne_bf16(w0), h1 = rne_bf16(w1), h2 = rne_bf16(w2), h3 = rne_bf16(w3);
        unsigned l0 = rne_bf16(w0 - bf16_dec(h0)), l1 = rne_bf16(w1 - bf16_dec(h1));
        unsigned l2 = rne_bf16(w2 - bf16_dec(h2)), l3 = rne_bf16(w3 - bf16_dec(h3));
        wpred[i * 2 + 0] = make_uint4(h0 | (h1 << 16), h2 | (h3 << 16),
                                      l0 | (l1 << 16), l2 | (l3 << 16));   // [ah, al]
        wpred[i * 2 + 1] = make_uint4(h0 | (h1 << 16), h2 | (h3 << 16),
                                      onepk, npk);                          // [ah, 1,1, Pnh,Pnl]
    }
    {   // plain tgt record (col side)
        float4 v = tgt[i];
        float n = fmaf(v.x, v.x, fmaf(v.y, v.y, fmaf(v.z, v.z, 0.5f * v.w * v.w)));
        unsigned nh = rne_bf16(n);
        unsigned nl = rne_bf16(n - bf16_dec(nh));
        unsigned npk = nh | (nl << 16);
        unsigned g0 = rne_bf16(v.x), g1 = rne_bf16(v.y), g2 = rne_bf16(v.z), g3 = rne_bf16(v.w);
        unsigned m0 = rne_bf16(v.x - bf16_dec(g0)), m1 = rne_bf16(v.y - bf16_dec(g1));
        unsigned m2 = rne_bf16(v.z - bf16_dec(g2)), m3 = rne_bf16(v.w - bf16_dec(g3));
        ptgt[i * 2 + 0] = make_uint4(g0 | (g1 << 16), g2 | (g3 << 16),
                                     g0 | (g1 << 16), g2 | (g3 << 16));     // [bh, bh]
        ptgt[i * 2 + 1] = make_uint4(m0 | (m1 << 16), m2 | (m3 << 16),
                                     npk, onepk);                           // [bl, Tnh,Tnl, 1,1]
    }
}

// R7-R9 root cause (revised): mc[] never got SROA'd into registers (scratch
// from IR level -> 5-8 GB FETCH), independent of launch bounds / sched
// barriers. Fix: col-min state = 16 NAMED SCALARS (always promotable) with
// fully-literal-index reduction macros; col partials flushed once via LDS
// atomicMin on uint bits (clamp>=0 before cast keeps uint order == float
// order; max(.,0) commutes with min). Rows keep R6-proven mr[] arrays.
__global__ __launch_bounds__(256, 4) void chamfer_mfma_kernel(
    const bf16x8* __restrict__ wpred, const bf16x8* __restrict__ ptgt,
    unsigned int* __restrict__ minbuf)
{
    __shared__ unsigned colLds[CPB];   // block-wide col-min partials (bits)
    __shared__ float red[RPB];         // block-wide row mins

    for (int c = threadIdx.x; c < CPB; c += 256) colLds[c] = 0x7f7f7f7fu;
    __syncthreads();

    const int lane = threadIdx.x & 63;
    const int wave = threadIdx.x >> 6;
    const int half = lane >> 5;     // selects k0-7 vs k8-15 record
    const int lid  = lane & 31;

    const int rowBase = blockIdx.x * RPB + wave * 64;
    const int colBase = blockIdx.y * CPB;

    bf16x8 a0 = wpred[(rowBase +      lid) * 2 + half];
    bf16x8 a1 = wpred[(rowBase + 32 + lid) * 2 + half];

    float mr0[16], mr1[16];
#pragma unroll
    for (int r = 0; r < 16; ++r) { mr0[r] = 3.0e38f; mr1[r] = 3.0e38f; }

    float mc0 = 3.0e38f, mc1 = 3.0e38f, mc2 = 3.0e38f, mc3 = 3.0e38f,
          mc4 = 3.0e38f, mc5 = 3.0e38f, mc6 = 3.0e38f, mc7 = 3.0e38f,
          mc8 = 3.0e38f, mc9 = 3.0e38f, mc10 = 3.0e38f, mc11 = 3.0e38f,
          mc12 = 3.0e38f, mc13 = 3.0e38f, mc14 = 3.0e38f, mc15 = 3.0e38f;

    const bf16x8* bp = ptgt + (colBase + lid) * 2 + half;
    const f32x16 kZero = (f32x16)(0.0f);

// literal-index tree reduce of one acc into a named scalar (no arrays)
#define COLRED(MC, ACC)                                                    \
    {                                                                      \
        float c01 = fminf(ACC[0], ACC[1]),   c23 = fminf(ACC[2], ACC[3]);  \
        float c45 = fminf(ACC[4], ACC[5]),   c67 = fminf(ACC[6], ACC[7]);  \
        float c89 = fminf(ACC[8], ACC[9]),   cab = fminf(ACC[10], ACC[11]);\
        float ccd = fminf(ACC[12], ACC[13]), cef = fminf(ACC[14], ACC[15]);\
        float q0 = fminf(fminf(c01, c23), fminf(c45, c67));                \
        float q1 = fminf(fminf(c89, cab), fminf(ccd, cef));                \
        MC = fminf(fminf(q0, q1), MC);                                     \
    }

#define HALFSTEP(AF, MR, B0, B1, MCA, MCB)                                        \
    {                                                                             \
        f32x16 acc0 = __builtin_amdgcn_mfma_f32_32x32x16_bf16(AF, B0, kZero, 0, 0, 0); \
        f32x16 acc1 = __builtin_amdgcn_mfma_f32_32x32x16_bf16(AF, B1, kZero, 0, 0, 0); \
        _Pragma("unroll")                                                         \
        for (int r = 0; r < 16; ++r)                                              \
            MR[r] = fminf(fminf(acc0[r], acc1[r]), MR[r]);                        \
        COLRED(MCA, acc0)                                                         \
        COLRED(MCB, acc1)                                                         \
        __builtin_amdgcn_sched_barrier(0x20); /* only VMEM_READ may cross */      \
    }

#define STEP(TP, MCA, MCB)                                                        \
    {                                                                             \
        bf16x8 b0 = bp[(2 * (TP)) * 64];                                          \
        bf16x8 b1 = bp[(2 * (TP) + 1) * 64];                                      \
        HALFSTEP(a0, mr0, b0, b1, MCA, MCB)                                       \
        HALFSTEP(a1, mr1, b0, b1, MCA, MCB)                                       \
    }

    STEP(0, mc0, mc1)   STEP(1, mc2, mc3)   STEP(2, mc4, mc5)   STEP(3, mc6, mc7)
    STEP(4, mc8, mc9)   STEP(5, mc10, mc11) STEP(6, mc12, mc13) STEP(7, mc14, mc15)
#undef STEP
#undef HALFSTEP
#undef COLRED

    // col partials -> LDS atomicMin (clamped bits; 2 lanes/col contend, cheap)
#define COLFLUSH(T, MC) \
    atomicMin(&colLds[(T) * 32 + lid], __float_as_uint(fmaxf(MC, 0.0f)));
    COLFLUSH(0, mc0)   COLFLUSH(1, mc1)   COLFLUSH(2, mc2)   COLFLUSH(3, mc3)
    COLFLUSH(4, mc4)   COLFLUSH(5, mc5)   COLFLUSH(6, mc6)   COLFLUSH(7, mc7)
    COLFLUSH(8, mc8)   COLFLUSH(9, mc9)   COLFLUSH(10, mc10) COLFLUSH(11, mc11)
    COLFLUSH(12, mc12) COLFLUSH(13, mc13) COLFLUSH(14, mc14) COLFLUSH(15, mc15)
#undef COLFLUSH

    // row mins: cross-lane min over the 32 col-lanes
    // C/D layout: col=lane&31, row=(reg&3)+8*(reg>>2)+4*(lane>>5)
#pragma unroll
    for (int r = 0; r < 16; ++r) {
        float v0 = mr0[r], v1 = mr1[r];
        v0 = fminf(v0, __shfl_xor(v0, 16)); v1 = fminf(v1, __shfl_xor(v1, 16));
        v0 = fminf(v0, __shfl_xor(v0, 8));  v1 = fminf(v1, __shfl_xor(v1, 8));
        v0 = fminf(v0, __shfl_xor(v0, 4));  v1 = fminf(v1, __shfl_xor(v1, 4));
        v0 = fminf(v0, __shfl_xor(v0, 2));  v1 = fminf(v1, __shfl_xor(v1, 2));
        v0 = fminf(v0, __shfl_xor(v0, 1));  v1 = fminf(v1, __shfl_xor(v1, 1));
        if (lid == 0) {
            int row = (r & 3) + 8 * (r >> 2) + 4 * half;
            red[wave * 64 + row]      = v0;
            red[wave * 64 + 32 + row] = v1;
        }
    }
    __syncthreads();

    {   // one row per thread -> global
        float v = fmaxf(red[threadIdx.x], 0.0f);
        atomicMin(&minbuf[blockIdx.x * RPB + threadIdx.x], __float_as_uint(v));
    }
#pragma unroll
    for (int s = 0; s < 2; ++s) {   // two cols per thread -> global
        int c = threadIdx.x + s * 256;
        atomicMin(&minbuf[NPTS + colBase + c], colLds[c]);
    }
}

__global__ __launch_bounds__(1024) void chamfer_reduce_kernel(
    const unsigned int* __restrict__ minbuf, float* __restrict__ out)
{
    __shared__ float red[16];
    const uint4* mb4 = (const uint4*)minbuf;
    float s = 0.0f;
#pragma unroll
    for (int it = 0; it < (2 * NPTS / 4) / 1024; ++it) {
        uint4 u = mb4[it * 1024 + threadIdx.x];
        s += __uint_as_float(u.x) + __uint_as_float(u.y)
           + __uint_as_float(u.z) + __uint_as_float(u.w);
    }
#pragma unroll
    for (int off = 32; off > 0; off >>= 1)
        s += __shfl_down(s, off);
    const int wave = threadIdx.x >> 6;
    const int lane = threadIdx.x & 63;
    if (lane == 0) red[wave] = s;
    __syncthreads();
    if (threadIdx.x == 0) {
        float t = 0.0f;
#pragma unroll
        for (int w = 0; w < 16; ++w) t += red[w];
        out[0] = t * (1.0f / (float)NPTS);
    }
}

extern "C" void kernel_launch(void* const* d_in, const int* in_sizes, int n_in,
                              void* d_out, int out_size, void* d_ws, size_t ws_size,
                              hipStream_t stream) {
    const float4* pred = (const float4*)d_in[0];
    const float4* tgt  = (const float4*)d_in[1];

    unsigned int* minbuf = (unsigned int*)d_ws;                 // 128 KB
    uint4* wpred = (uint4*)((char*)d_ws + 2 * NPTS * 4);        // 512 KB
    uint4* ptgt  = wpred + 2 * NPTS;                            // 512 KB

    prep_kernel<<<NPTS / 256, 256, 0, stream>>>(pred, tgt, wpred, ptgt, minbuf);

    dim3 grid(NRB, NCB);   // (64, 32) = 2048 blocks, single pass over M
    chamfer_mfma_kernel<<<grid, 256, 0, stream>>>(
        (const bf16x8*)wpred, (const bf16x8*)ptgt, minbuf);

    chamfer_reduce_kernel<<<1, 1024, 0, stream>>>(minbuf, (float*)d_out);
}

// Round 11
// 37.367 us; speedup vs baseline: 49.8422x; 49.8422x over previous
//
#include <hip/hip_runtime.h>

#define NPTS   16384
#define RPB    256      // rows per block (4 waves x 64)
#define CPB    512      // cols per block
#define NRB    (NPTS / RPB)   // 64
#define NCB    (NPTS / CPB)   // 32

typedef short  bf16x8 __attribute__((ext_vector_type(8)));
typedef float  f32x16 __attribute__((ext_vector_type(16)));

// ---- bf16 split helpers (RNE) ----
__device__ __forceinline__ unsigned rne_bf16(float f) {
    unsigned u = __float_as_uint(f);
    return (u + 0x7fffu + ((u >> 16) & 1u)) >> 16;
}
__device__ __forceinline__ float bf16_dec(unsigned h) {
    return __uint_as_float(h << 16);
}
#define ONE_BF 0x3f80u

// min3-tree over one acc's 16 elements (all literal indices -> pure registers)
__device__ __forceinline__ float tree16_min(f32x16 a) {
    float x0 = fminf(fminf(a[0],  a[1]),  a[2]);    // v_min3 x5
    float x1 = fminf(fminf(a[3],  a[4]),  a[5]);
    float x2 = fminf(fminf(a[6],  a[7]),  a[8]);
    float x3 = fminf(fminf(a[9],  a[10]), a[11]);
    float x4 = fminf(fminf(a[12], a[13]), a[14]);
    float y0 = fminf(fminf(x0, x1), x2);            // v_min3 x2
    float y1 = fminf(fminf(x3, x4), a[15]);
    return fminf(y0, y1);
}

// K=16 slot map (A = weighted pred, B = plain tgt):
//  k0-3: ah*bh  k4-7: al*bh  k8-11: ah*bl  k12-13: 1*Tnh,1*Tnl  k14-15: Pnh*1,Pnl*1
// => acc = hi-precision dot + Tn_j + Pn_i = combined(i,j) directly.
// combined() is symmetric in (pred,tgt): row-mins of M = min_p2g,
// col-mins of M = min_g2p. ONE pass serves both directions.

__global__ __launch_bounds__(256) void prep_kernel(
    const float4* __restrict__ pred, const float4* __restrict__ tgt,
    uint4* __restrict__ wpred, uint4* __restrict__ ptgt,
    unsigned int* __restrict__ minbuf)
{
    int i = blockIdx.x * 256 + threadIdx.x;
    if (i >= NPTS) return;

    minbuf[i]        = 0x7f7f7f7fu;   // 3.39e38f
    minbuf[i + NPTS] = 0x7f7f7f7fu;

    unsigned onepk = ONE_BF | (ONE_BF << 16);

    {   // weighted pred record (row side)
        float4 v = pred[i];
        float n = fmaf(v.x, v.x, fmaf(v.y, v.y, fmaf(v.z, v.z, 0.5f * v.w * v.w)));
        unsigned nh = rne_bf16(n);
        unsigned nl = rne_bf16(n - bf16_dec(nh));
        unsigned npk = nh | (nl << 16);
        float w0 = -2.0f * v.x, w1 = -2.0f * v.y, w2 = -2.0f * v.z, w3 = -v.w;
        unsigned h0 = rne_bf16(w0), h1 = rne_bf16(w1), h2 = rne_bf16(w2), h3 = rne_bf16(w3);
        unsigned l0 = rne_bf16(w0 - bf16_dec(h0)), l1 = rne_bf16(w1 - bf16_dec(h1));
        unsigned l2 = rne_bf16(w2 - bf16_dec(h2)), l3 = rne_bf16(w3 - bf16_dec(h3));
        wpred[i * 2 + 0] = make_uint4(h0 | (h1 << 16), h2 | (h3 << 16),
                                      l0 | (l1 << 16), l2 | (l3 << 16));   // [ah, al]
        wpred[i * 2 + 1] = make_uint4(h0 | (h1 << 16), h2 | (h3 << 16),
                                      onepk, npk);                          // [ah, 1,1, Pnh,Pnl]
    }
    {   // plain tgt record (col side)
        float4 v = tgt[i];
        float n = fmaf(v.x, v.x, fmaf(v.y, v.y, fmaf(v.z, v.z, 0.5f * v.w * v.w)));
        unsigned nh = rne_bf16(n);
        unsigned nl = rne_bf16(n - bf16_dec(nh));
        unsigned npk = nh | (nl << 16);
        unsigned g0 = rne_bf16(v.x), g1 = rne_bf16(v.y), g2 = rne_bf16(v.z), g3 = rne_bf16(v.w);
        unsigned m0 = rne_bf16(v.x - bf16_dec(g0)), m1 = rne_bf16(v.y - bf16_dec(g1));
        unsigned m2 = rne_bf16(v.z - bf16_dec(g2)), m3 = rne_bf16(v.w - bf16_dec(g3));
        ptgt[i * 2 + 0] = make_uint4(g0 | (g1 << 16), g2 | (g3 << 16),
                                     g0 | (g1 << 16), g2 | (g3 << 16));     // [bh, bh]
        ptgt[i * 2 + 1] = make_uint4(m0 | (m1 << 16), m2 | (m3 << 16),
                                     npk, onepk);                           // [bl, Tnh,Tnl, 1,1]
    }
}

// Single-pass over M. Codegen lesson from R7-R10: keep ALL unrolled loops in
// real source (macro _Pragma loops failed to unroll -> runtime ext_vector
// extracts -> scratch, 5-8 GB FETCH). Col-mins have NO persistent register
// state: per-iteration min3-tree (literal indices) -> immediate LDS atomicMin
// on clamped uint bits (uint order == float order for values >= 0).
__global__ __launch_bounds__(256, 2) void chamfer_mfma_kernel(
    const bf16x8* __restrict__ wpred, const bf16x8* __restrict__ ptgt,
    unsigned int* __restrict__ minbuf)
{
    __shared__ unsigned colLds[CPB];   // block-wide col mins (clamped bits)
    __shared__ float red[RPB];         // block-wide row mins

    for (int c = threadIdx.x; c < CPB; c += 256) colLds[c] = 0x7f7f7f7fu;
    __syncthreads();

    const int lane = threadIdx.x & 63;
    const int wave = threadIdx.x >> 6;
    const int half = lane >> 5;     // selects k0-7 vs k8-15 record
    const int lid  = lane & 31;

    const int rowBase = blockIdx.x * RPB + wave * 64;
    const int colBase = blockIdx.y * CPB;

    bf16x8 a0 = wpred[(rowBase +      lid) * 2 + half];
    bf16x8 a1 = wpred[(rowBase + 32 + lid) * 2 + half];

    float mr0[16], mr1[16];
#pragma unroll
    for (int r = 0; r < 16; ++r) { mr0[r] = 3.0e38f; mr1[r] = 3.0e38f; }

    const bf16x8* bp = ptgt + (colBase + lid) * 2 + half;
    const f32x16 kZero = (f32x16)(0.0f);

#pragma unroll 2
    for (int t = 0; t < CPB / 64; ++t) {
        bf16x8 b0 = bp[t * 128];
        bf16x8 b1 = bp[t * 128 + 64];

        // row-tile 0 (rows 0-31)
        f32x16 A0 = __builtin_amdgcn_mfma_f32_32x32x16_bf16(a0, b0, kZero, 0, 0, 0);
        f32x16 A1 = __builtin_amdgcn_mfma_f32_32x32x16_bf16(a0, b1, kZero, 0, 0, 0);
#pragma unroll
        for (int r = 0; r < 16; ++r)
            mr0[r] = fminf(fminf(A0[r], A1[r]), mr0[r]);   // v_min3
        float ta = tree16_min(A0);
        float tb = tree16_min(A1);

        // row-tile 1 (rows 32-63)
        f32x16 B0 = __builtin_amdgcn_mfma_f32_32x32x16_bf16(a1, b0, kZero, 0, 0, 0);
        f32x16 B1 = __builtin_amdgcn_mfma_f32_32x32x16_bf16(a1, b1, kZero, 0, 0, 0);
#pragma unroll
        for (int r = 0; r < 16; ++r)
            mr1[r] = fminf(fminf(B0[r], B1[r]), mr1[r]);
        ta = fminf(ta, tree16_min(B0));
        tb = fminf(tb, tree16_min(B1));

        // immediate col flush: col = colBase + t*64 + (0|32) + lid
        atomicMin(&colLds[t * 64 +      lid], __float_as_uint(fmaxf(ta, 0.0f)));
        atomicMin(&colLds[t * 64 + 32 + lid], __float_as_uint(fmaxf(tb, 0.0f)));
    }

    // row mins: cross-lane min over the 32 col-lanes
    // C/D layout: col=lane&31, row=(reg&3)+8*(reg>>2)+4*(lane>>5)
#pragma unroll
    for (int r = 0; r < 16; ++r) {
        float v0 = mr0[r], v1 = mr1[r];
        v0 = fminf(v0, __shfl_xor(v0, 16)); v1 = fminf(v1, __shfl_xor(v1, 16));
        v0 = fminf(v0, __shfl_xor(v0, 8));  v1 = fminf(v1, __shfl_xor(v1, 8));
        v0 = fminf(v0, __shfl_xor(v0, 4));  v1 = fminf(v1, __shfl_xor(v1, 4));
        v0 = fminf(v0, __shfl_xor(v0, 2));  v1 = fminf(v1, __shfl_xor(v1, 2));
        v0 = fminf(v0, __shfl_xor(v0, 1));  v1 = fminf(v1, __shfl_xor(v1, 1));
        if (lid == 0) {
            int row = (r & 3) + 8 * (r >> 2) + 4 * half;
            red[wave * 64 + row]      = v0;
            red[wave * 64 + 32 + row] = v1;
        }
    }
    __syncthreads();

    {   // one row per thread -> global
        float v = fmaxf(red[threadIdx.x], 0.0f);
        atomicMin(&minbuf[blockIdx.x * RPB + threadIdx.x], __float_as_uint(v));
    }
#pragma unroll
    for (int s = 0; s < 2; ++s) {   // two cols per thread -> global
        int c = threadIdx.x + s * 256;
        atomicMin(&minbuf[NPTS + colBase + c], colLds[c]);
    }
}

__global__ __launch_bounds__(1024) void chamfer_reduce_kernel(
    const unsigned int* __restrict__ minbuf, float* __restrict__ out)
{
    __shared__ float red[16];
    const uint4* mb4 = (const uint4*)minbuf;
    float s = 0.0f;
#pragma unroll
    for (int it = 0; it < (2 * NPTS / 4) / 1024; ++it) {
        uint4 u = mb4[it * 1024 + threadIdx.x];
        s += __uint_as_float(u.x) + __uint_as_float(u.y)
           + __uint_as_float(u.z) + __uint_as_float(u.w);
    }
#pragma unroll
    for (int off = 32; off > 0; off >>= 1)
        s += __shfl_down(s, off);
    const int wave = threadIdx.x >> 6;
    const int lane = threadIdx.x & 63;
    if (lane == 0) red[wave] = s;
    __syncthreads();
    if (threadIdx.x == 0) {
        float t = 0.0f;
#pragma unroll
        for (int w = 0; w < 16; ++w) t += red[w];
        out[0] = t * (1.0f / (float)NPTS);
    }
}

extern "C" void kernel_launch(void* const* d_in, const int* in_sizes, int n_in,
                              void* d_out, int out_size, void* d_ws, size_t ws_size,
                              hipStream_t stream) {
    const float4* pred = (const float4*)d_in[0];
    const float4* tgt  = (const float4*)d_in[1];

    unsigned int* minbuf = (unsigned int*)d_ws;                 // 128 KB
    uint4* wpred = (uint4*)((char*)d_ws + 2 * NPTS * 4);        // 512 KB
    uint4* ptgt  = wpred + 2 * NPTS;                            // 512 KB

    prep_kernel<<<NPTS / 256, 256, 0, stream>>>(pred, tgt, wpred, ptgt, minbuf);

    dim3 grid(NRB, NCB);   // (64, 32) = 2048 blocks, single pass over M
    chamfer_mfma_kernel<<<grid, 256, 0, stream>>>(
        (const bf16x8*)wpred, (const bf16x8*)ptgt, minbuf);

    chamfer_reduce_kernel<<<1, 1024, 0, stream>>>(minbuf, (float*)d_out);
}

// Round 12
// 36.141 us; speedup vs baseline: 51.5330x; 1.0339x over previous
//
#include <hip/hip_runtime.h>

#define NPTS   16384
#define RPB    256      // rows per block (4 waves x 64)
#define CPB    512      // cols per block
#define NRB    (NPTS / RPB)   // 64
#define NCB    (NPTS / CPB)   // 32

typedef short  bf16x8 __attribute__((ext_vector_type(8)));
typedef float  f32x16 __attribute__((ext_vector_type(16)));

// ---- bf16 split helpers (RNE) ----
__device__ __forceinline__ unsigned rne_bf16(float f) {
    unsigned u = __float_as_uint(f);
    return (u + 0x7fffu + ((u >> 16) & 1u)) >> 16;
}
__device__ __forceinline__ float bf16_dec(unsigned h) {
    return __uint_as_float(h << 16);
}
#define ONE_BF 0x3f80u

// min3-tree over one acc's 16 elements (all literal indices -> pure registers)
__device__ __forceinline__ float tree16_min(f32x16 a) {
    float x0 = fminf(fminf(a[0],  a[1]),  a[2]);    // v_min3 x5
    float x1 = fminf(fminf(a[3],  a[4]),  a[5]);
    float x2 = fminf(fminf(a[6],  a[7]),  a[8]);
    float x3 = fminf(fminf(a[9],  a[10]), a[11]);
    float x4 = fminf(fminf(a[12], a[13]), a[14]);
    float y0 = fminf(fminf(x0, x1), x2);            // v_min3 x2
    float y1 = fminf(fminf(x3, x4), a[15]);
    return fminf(y0, y1);
}

// K=16 slot map (A = weighted pred, B = plain tgt):
//  k0-3: ah*bh  k4-7: al*bh  k8-11: ah*bl  k12-13: 1*Tnh,1*Tnl  k14-15: Pnh*1,Pnl*1
// => acc = hi-precision dot + Tn_j + Pn_i = combined(i,j) directly.
// combined() is symmetric in (pred,tgt): row-mins of M = min_p2g,
// col-mins of M = min_g2p. ONE pass serves both directions.

__global__ __launch_bounds__(256) void prep_kernel(
    const float4* __restrict__ pred, const float4* __restrict__ tgt,
    uint4* __restrict__ wpred, uint4* __restrict__ ptgt,
    unsigned int* __restrict__ minbuf)
{
    int i = blockIdx.x * 256 + threadIdx.x;
    if (i >= NPTS) return;

    minbuf[i]        = 0x7f7f7f7fu;   // 3.39e38f
    minbuf[i + NPTS] = 0x7f7f7f7fu;

    unsigned onepk = ONE_BF | (ONE_BF << 16);

    {   // weighted pred record (row side)
        float4 v = pred[i];
        float n = fmaf(v.x, v.x, fmaf(v.y, v.y, fmaf(v.z, v.z, 0.5f * v.w * v.w)));
        unsigned nh = rne_bf16(n);
        unsigned nl = rne_bf16(n - bf16_dec(nh));
        unsigned npk = nh | (nl << 16);
        float w0 = -2.0f * v.x, w1 = -2.0f * v.y, w2 = -2.0f * v.z, w3 = -v.w;
        unsigned h0 = rne_bf16(w0), h1 = rne_bf16(w1), h2 = rne_bf16(w2), h3 = rne_bf16(w3);
        unsigned l0 = rne_bf16(w0 - bf16_dec(h0)), l1 = rne_bf16(w1 - bf16_dec(h1));
        unsigned l2 = rne_bf16(w2 - bf16_dec(h2)), l3 = rne_bf16(w3 - bf16_dec(h3));
        wpred[i * 2 + 0] = make_uint4(h0 | (h1 << 16), h2 | (h3 << 16),
                                      l0 | (l1 << 16), l2 | (l3 << 16));   // [ah, al]
        wpred[i * 2 + 1] = make_uint4(h0 | (h1 << 16), h2 | (h3 << 16),
                                      onepk, npk);                          // [ah, 1,1, Pnh,Pnl]
    }
    {   // plain tgt record (col side)
        float4 v = tgt[i];
        float n = fmaf(v.x, v.x, fmaf(v.y, v.y, fmaf(v.z, v.z, 0.5f * v.w * v.w)));
        unsigned nh = rne_bf16(n);
        unsigned nl = rne_bf16(n - bf16_dec(nh));
        unsigned npk = nh | (nl << 16);
        unsigned g0 = rne_bf16(v.x), g1 = rne_bf16(v.y), g2 = rne_bf16(v.z), g3 = rne_bf16(v.w);
        unsigned m0 = rne_bf16(v.x - bf16_dec(g0)), m1 = rne_bf16(v.y - bf16_dec(g1));
        unsigned m2 = rne_bf16(v.z - bf16_dec(g2)), m3 = rne_bf16(v.w - bf16_dec(g3));
        ptgt[i * 2 + 0] = make_uint4(g0 | (g1 << 16), g2 | (g3 << 16),
                                     g0 | (g1 << 16), g2 | (g3 << 16));     // [bh, bh]
        ptgt[i * 2 + 1] = make_uint4(m0 | (m1 << 16), m2 | (m3 << 16),
                                     npk, onepk);                           // [bl, Tnh,Tnl, 1,1]
    }
}

// R11 (this structure, (256,2)) passed with no spill but ran latency-bound at
// 2 waves/SIMD. R12: (256,4) for <=128 VGPR / 4 waves per SIMD. Live set ~90
// regs: one acc-pair + mr0/mr1 + frags. sched_barrier(0x20) after each
// acc-pair consumption caps acc live ranges (VMEM_READ prefetch may cross).
// Spill detector: FETCH_SIZE must stay ~tens of MB (GB-scale => scratch).
__global__ __launch_bounds__(256, 4) void chamfer_mfma_kernel(
    const bf16x8* __restrict__ wpred, const bf16x8* __restrict__ ptgt,
    unsigned int* __restrict__ minbuf)
{
    __shared__ unsigned colLds[CPB];   // block-wide col mins (clamped bits)
    __shared__ float red[RPB];         // block-wide row mins

    for (int c = threadIdx.x; c < CPB; c += 256) colLds[c] = 0x7f7f7f7fu;
    __syncthreads();

    const int lane = threadIdx.x & 63;
    const int wave = threadIdx.x >> 6;
    const int half = lane >> 5;     // selects k0-7 vs k8-15 record
    const int lid  = lane & 31;

    const int rowBase = blockIdx.x * RPB + wave * 64;
    const int colBase = blockIdx.y * CPB;

    bf16x8 a0 = wpred[(rowBase +      lid) * 2 + half];
    bf16x8 a1 = wpred[(rowBase + 32 + lid) * 2 + half];

    float mr0[16], mr1[16];
#pragma unroll
    for (int r = 0; r < 16; ++r) { mr0[r] = 3.0e38f; mr1[r] = 3.0e38f; }

    const bf16x8* bp = ptgt + (colBase + lid) * 2 + half;
    const f32x16 kZero = (f32x16)(0.0f);

#pragma unroll 2
    for (int t = 0; t < CPB / 64; ++t) {
        bf16x8 b0 = bp[t * 128];
        bf16x8 b1 = bp[t * 128 + 64];

        // row-tile 0 (rows 0-31)
        f32x16 A0 = __builtin_amdgcn_mfma_f32_32x32x16_bf16(a0, b0, kZero, 0, 0, 0);
        f32x16 A1 = __builtin_amdgcn_mfma_f32_32x32x16_bf16(a0, b1, kZero, 0, 0, 0);
#pragma unroll
        for (int r = 0; r < 16; ++r)
            mr0[r] = fminf(fminf(A0[r], A1[r]), mr0[r]);   // v_min3
        float ta = tree16_min(A0);
        float tb = tree16_min(A1);
        __builtin_amdgcn_sched_barrier(0x20);   // retire A0/A1; loads may cross

        // row-tile 1 (rows 32-63)
        f32x16 B0 = __builtin_amdgcn_mfma_f32_32x32x16_bf16(a1, b0, kZero, 0, 0, 0);
        f32x16 B1 = __builtin_amdgcn_mfma_f32_32x32x16_bf16(a1, b1, kZero, 0, 0, 0);
#pragma unroll
        for (int r = 0; r < 16; ++r)
            mr1[r] = fminf(fminf(B0[r], B1[r]), mr1[r]);
        ta = fminf(ta, tree16_min(B0));
        tb = fminf(tb, tree16_min(B1));
        __builtin_amdgcn_sched_barrier(0x20);   // retire B0/B1

        // immediate col flush: col = colBase + t*64 + (0|32) + lid
        atomicMin(&colLds[t * 64 +      lid], __float_as_uint(fmaxf(ta, 0.0f)));
        atomicMin(&colLds[t * 64 + 32 + lid], __float_as_uint(fmaxf(tb, 0.0f)));
    }

    // row mins: cross-lane min over the 32 col-lanes
    // C/D layout: col=lane&31, row=(reg&3)+8*(reg>>2)+4*(lane>>5)
#pragma unroll
    for (int r = 0; r < 16; ++r) {
        float v0 = mr0[r], v1 = mr1[r];
        v0 = fminf(v0, __shfl_xor(v0, 16)); v1 = fminf(v1, __shfl_xor(v1, 16));
        v0 = fminf(v0, __shfl_xor(v0, 8));  v1 = fminf(v1, __shfl_xor(v1, 8));
        v0 = fminf(v0, __shfl_xor(v0, 4));  v1 = fminf(v1, __shfl_xor(v1, 4));
        v0 = fminf(v0, __shfl_xor(v0, 2));  v1 = fminf(v1, __shfl_xor(v1, 2));
        v0 = fminf(v0, __shfl_xor(v0, 1));  v1 = fminf(v1, __shfl_xor(v1, 1));
        if (lid == 0) {
            int row = (r & 3) + 8 * (r >> 2) + 4 * half;
            red[wave * 64 + row]      = v0;
            red[wave * 64 + 32 + row] = v1;
        }
    }
    __syncthreads();

    {   // one row per thread -> global
        float v = fmaxf(red[threadIdx.x], 0.0f);
        atomicMin(&minbuf[blockIdx.x * RPB + threadIdx.x], __float_as_uint(v));
    }
#pragma unroll
    for (int s = 0; s < 2; ++s) {   // two cols per thread -> global
        int c = threadIdx.x + s * 256;
        atomicMin(&minbuf[NPTS + colBase + c], colLds[c]);
    }
}

__global__ __launch_bounds__(1024) void chamfer_reduce_kernel(
    const unsigned int* __restrict__ minbuf, float* __restrict__ out)
{
    __shared__ float red[16];
    const uint4* mb4 = (const uint4*)minbuf;
    float s = 0.0f;
#pragma unroll
    for (int it = 0; it < (2 * NPTS / 4) / 1024; ++it) {
        uint4 u = mb4[it * 1024 + threadIdx.x];
        s += __uint_as_float(u.x) + __uint_as_float(u.y)
           + __uint_as_float(u.z) + __uint_as_float(u.w);
    }
#pragma unroll
    for (int off = 32; off > 0; off >>= 1)
        s += __shfl_down(s, off);
    const int wave = threadIdx.x >> 6;
    const int lane = threadIdx.x & 63;
    if (lane == 0) red[wave] = s;
    __syncthreads();
    if (threadIdx.x == 0) {
        float t = 0.0f;
#pragma unroll
        for (int w = 0; w < 16; ++w) t += red[w];
        out[0] = t * (1.0f / (float)NPTS);
    }
}

extern "C" void kernel_launch(void* const* d_in, const int* in_sizes, int n_in,
                              void* d_out, int out_size, void* d_ws, size_t ws_size,
                              hipStream_t stream) {
    const float4* pred = (const float4*)d_in[0];
    const float4* tgt  = (const float4*)d_in[1];

    unsigned int* minbuf = (unsigned int*)d_ws;                 // 128 KB
    uint4* wpred = (uint4*)((char*)d_ws + 2 * NPTS * 4);        // 512 KB
    uint4* ptgt  = wpred + 2 * NPTS;                            // 512 KB

    prep_kernel<<<NPTS / 256, 256, 0, stream>>>(pred, tgt, wpred, ptgt, minbuf);

    dim3 grid(NRB, NCB);   // (64, 32) = 2048 blocks, single pass over M
    chamfer_mfma_kernel<<<grid, 256, 0, stream>>>(
        (const bf16x8*)wpred, (const bf16x8*)ptgt, minbuf);

    chamfer_reduce_kernel<<<1, 1024, 0, stream>>>(minbuf, (float*)d_out);
}